// Round 1
// 5277.900 us; speedup vs baseline: 3.5269x; 3.5269x over previous
//
#include <hip/hip_runtime.h>
#include <hip/hip_bf16.h>
#include <cstddef>
#include <type_traits>

typedef unsigned int u32;
typedef short bf16x8 __attribute__((ext_vector_type(8)));
typedef float f32x4 __attribute__((ext_vector_type(4)));
typedef _Float16 hf2 __attribute__((ext_vector_type(2)));

#define TC 256          // time-chunk length
#define NCHUNK 8        // 2048 / TC

// ---------- helpers ----------
__device__ __forceinline__ float sigf(float x) {
    return __builtin_amdgcn_rcpf(1.f + __expf(-x));
}
__device__ __forceinline__ float tanhf_fast(float x) {
    return 1.f - 2.f * __builtin_amdgcn_rcpf(1.f + __expf(2.f * x));
}
// fp16-pair dot with f32 accumulate: v_dot2_f32_f16 when available
__device__ __forceinline__ float dotp(u32 w, u32 h, float acc) {
#if __has_builtin(__builtin_amdgcn_fdot2)
    return __builtin_amdgcn_fdot2(__builtin_bit_cast(hf2, w),
                                  __builtin_bit_cast(hf2, h), acc, false);
#else
    hf2 wv = __builtin_bit_cast(hf2, w);
    hf2 hv = __builtin_bit_cast(hf2, h);
    return fmaf((float)wv.y, (float)hv.y, fmaf((float)wv.x, (float)hv.x, acc));
#endif
}
__device__ __forceinline__ float dot4(uint4 w, uint4 h, float acc) {
    acc = dotp(w.x, h.x, acc);
    acc = dotp(w.y, h.y, acc);
    acc = dotp(w.z, h.z, acc);
    acc = dotp(w.w, h.w, acc);
    return acc;
}

// ---------- dtype sniff: is this buffer bf16 (1) or fp32 (0)? ----------
__global__ void sniff(const u32* __restrict__ src, int nwords, int* __restrict__ flag) {
    __shared__ int cnt[256];
    int tid = threadIdx.x;
    size_t idx = (size_t)tid * (size_t)nwords / 256;
    u32 u = src[idx];
    int e = (u >> 7) & 0xFF;
    cnt[tid] = (e >= 100 && e <= 140) ? 1 : 0;
    __syncthreads();
    for (int s = 128; s > 0; s >>= 1) {
        if (tid < s) cnt[tid] += cnt[tid + s];
        __syncthreads();
    }
    if (tid == 0) *flag = (cnt[0] >= 144) ? 1 : 0;
}

// ---------- generic convert (bf16-or-f32 source) -> bf16 ----------
__global__ void conv_any(const void* __restrict__ src, __hip_bfloat16* __restrict__ dst,
                         int n, const int* __restrict__ flag) {
    int i = blockIdx.x * 256 + threadIdx.x;
    if (i >= n) return;
    if (*flag)
        dst[i] = ((const __hip_bfloat16*)src)[i];
    else
        dst[i] = __float2bfloat16(((const float*)src)[i]);
}

// ---------- per-chunk X convert: X[b][tc*256+ti][128] -> Xc_b[b][ti][128] ----------
__global__ void conv_x(const void* __restrict__ X, __hip_bfloat16* __restrict__ dst,
                       int tc, const int* __restrict__ flag) {
    int i = blockIdx.x * 256 + threadIdx.x;     // 2097152 total
    int b = i >> 15, rem = i & 32767, ti = rem >> 7, d = rem & 127;
    size_t s = ((size_t)(b * 2048 + tc * TC + ti) << 7) | d;
    float v = (*flag) ? __bfloat162float(((const __hip_bfloat16*)X)[s])
                      : ((const float*)X)[s];
    dst[i] = __float2bfloat16(v);
}

// ---------- pack Wh [256][1024] -> quad-major fp16-pair uint4 [32][1024] ----------
// Whq[q][n] = {pack(W[8q],W[8q+1]), pack(W[8q+2],W[8q+3]), pack(W[8q+4],W[8q+5]),
//              pack(W[8q+6],W[8q+7])} for column n.
__global__ void pack_whq(const void* __restrict__ Wh, uint4* __restrict__ Whq,
                         const int* __restrict__ flag) {
    int i = blockIdx.x * 256 + threadIdx.x;   // 32768 total
    int q = i >> 10, n = i & 1023;
    float w[8];
    if (*flag) {
        const __hip_bfloat16* p = (const __hip_bfloat16*)Wh;
#pragma unroll
        for (int j = 0; j < 8; ++j) w[j] = __bfloat162float(p[(8 * q + j) * 1024 + n]);
    } else {
        const float* p = (const float*)Wh;
#pragma unroll
        for (int j = 0; j < 8; ++j) w[j] = p[(8 * q + j) * 1024 + n];
    }
    u32 r[4];
#pragma unroll
    for (int pp = 0; pp < 4; ++pp) {
        hf2 hp; hp.x = (_Float16)w[2 * pp]; hp.y = (_Float16)w[2 * pp + 1];
        r[pp] = __builtin_bit_cast(u32, hp);
    }
    Whq[i] = make_uint4(r[0], r[1], r[2], r[3]);
}

// ---------- GEMM: C[row(m)][N] = A[m][K](bf16) @ B[K][N](bf16) + bias ----------
template <typename OutT>
__global__ void gemm_bias(const __hip_bfloat16* __restrict__ A,
                          const __hip_bfloat16* __restrict__ B,
                          const __hip_bfloat16* __restrict__ bias,
                          OutT* __restrict__ C, int N, int K,
                          long strideA, long strideC) {
    __shared__ short As[64 * 72];
    __shared__ short Bs[64 * 72];
    const int tid = threadIdx.x;
    const int n0 = blockIdx.x * 64;
    const int m0 = blockIdx.y * 64;
    const int w = tid >> 6, lane = tid & 63;
    const int lm = lane & 15, lq = lane >> 4;

    f32x4 acc[4];
#pragma unroll
    for (int i = 0; i < 4; ++i) acc[i] = (f32x4){0.f, 0.f, 0.f, 0.f};

    const int kchunks = K >> 6;
    for (int kc = 0; kc < kchunks; ++kc) {
#pragma unroll
        for (int p = 0; p < 2; ++p) {
            int m = m0 + (tid >> 3) + 32 * p;
            int ch = tid & 7;
            size_t aoff = ((size_t)(m >> 8) * strideA + (m & 255)) * K;
            uint4 v = *(const uint4*)(A + aoff + kc * 64 + ch * 8);
            *(uint4*)(As + ((tid >> 3) + 32 * p) * 72 + ch * 8) = v;
        }
#pragma unroll
        for (int p = 0; p < 2; ++p) {
            int k  = (tid >> 3) + 32 * p;
            int ne = (tid & 7) * 8;
            uint4 v = *(const uint4*)(B + (size_t)(kc * 64 + k) * N + n0 + ne);
            const short* sv = (const short*)&v;
#pragma unroll
            for (int e = 0; e < 8; ++e) Bs[(ne + e) * 72 + k] = sv[e];
        }
        __syncthreads();
#pragma unroll
        for (int ks = 0; ks < 2; ++ks) {
            bf16x8 af = *(const bf16x8*)(As + (16 * w + lm) * 72 + ks * 32 + lq * 8);
#pragma unroll
            for (int nt = 0; nt < 4; ++nt) {
                bf16x8 bfr = *(const bf16x8*)(Bs + (nt * 16 + lm) * 72 + ks * 32 + lq * 8);
                acc[nt] = __builtin_amdgcn_mfma_f32_16x16x32_bf16(af, bfr, acc[nt], 0, 0, 0);
            }
        }
        __syncthreads();
    }
#pragma unroll
    for (int nt = 0; nt < 4; ++nt) {
        int col = n0 + nt * 16 + lm;
        float bv = __bfloat162float(bias[col]);
#pragma unroll
        for (int r = 0; r < 4; ++r) {
            int mrow = m0 + 16 * w + lq * 4 + r;
            size_t coff = ((size_t)(mrow >> 8) * strideC + (mrow & 255)) * N;
            float v = acc[nt][r] + bv;
            if constexpr (std::is_same_v<OutT, _Float16>)
                C[coff + col] = (_Float16)v;
            else if constexpr (std::is_same_v<OutT, float>)
                C[coff + col] = v;
            else
                C[coff + col] = __float2bfloat16(v);
        }
    }
}

// ---------- LSTM recurrence chunk: one WG (1024 threads) per batch ----------
// Weight quads (k-pair groups of 4 = 8 k-values): 32 total.
//   q in [0,LDSQ)            : staged in LDS (ds_read_b128)
//   q in [LDSQ,LDSQ+REGQ)    : resident in VGPRs
//   q in [LDSQ+REGQ,32)      : streamed from L2 via global_load_dwordx4
#define LDSQ 3
#define REGQ 8
#define STRQ (32 - LDSQ - REGQ)   // 21

__global__ __launch_bounds__(1024) void lstm_rec_chunk(
        const _Float16* __restrict__ xg_c,    // [64][TC][1024]
        const uint4* __restrict__ Whq,        // [32][1024] fp16-pair quads
        __hip_bfloat16* __restrict__ hs_c,    // [64][TC][256]
        float* __restrict__ hstate,           // [64][256]
        float* __restrict__ cstate,           // [64][256]
        int first) {
    const int tid = threadIdx.x;
    const int b = blockIdx.x;
    __shared__ uint4 wlds[LDSQ * 1024];           // 48 KB
    __shared__ float garr[1024];                  // 4 KB
    __shared__ alignas(16) u32 hpair[128];        // h as fp16 pairs, 512 B

#pragma unroll
    for (int q = 0; q < LDSQ; ++q) wlds[q * 1024 + tid] = Whq[q * 1024 + tid];
    uint4 wq[REGQ];
#pragma unroll
    for (int r = 0; r < REGQ; ++r) wq[r] = Whq[(LDSQ + r) * 1024 + tid];

    float c = 0.f;
    if (tid < 256) {
        float h0 = first ? 0.f : hstate[b * 256 + tid];
        if (!first) c = cstate[b * 256 + tid];
        float hp = __shfl_xor(h0, 1);
        if (!(tid & 1)) {
            hf2 p; p.x = (_Float16)h0; p.y = (_Float16)hp;
            hpair[tid >> 1] = __builtin_bit_cast(u32, p);
        }
    }
    __syncthreads();

    const uint4* wstr = Whq + (LDSQ + REGQ) * 1024 + tid;
    const _Float16* xgp = xg_c + (size_t)b * TC * 1024 + tid;
    __hip_bfloat16* hsp = hs_c + (size_t)b * TC * 256 + (tid & 255);
    const uint4* hq4 = (const uint4*)hpair;

    for (int t = 0; t < TC; ++t) {
        float acc[4];
        acc[0] = (float)xgp[(size_t)t * 1024];
        acc[1] = 0.f; acc[2] = 0.f; acc[3] = 0.f;
#pragma unroll
        for (int q = 0; q < 32; ++q) {
            uint4 hv = hq4[q];                         // broadcast ds_read_b128
            uint4 wv;
            if (q < LDSQ)            wv = wlds[q * 1024 + tid];
            else if (q < LDSQ + REGQ) wv = wq[q - LDSQ];
            else                      wv = wstr[(q - LDSQ - REGQ) * 1024];
            acc[q & 3] = dot4(wv, hv, acc[q & 3]);
        }
        float g = (acc[0] + acc[1]) + (acc[2] + acc[3]);

        // gates: [0,256)=forget [256,512)=input [512,768)=output [768,1024)=cell
        float s = (tid < 768) ? sigf(g) : tanhf_fast(g);
        garr[tid] = s;
        __syncthreads();
        if (tid < 256) {
            float f  = garr[tid];
            float ig = garr[tid + 256];
            float og = garr[tid + 512];
            float ct = garr[tid + 768];
            c = c * f + ct * ig;
            float h = og * tanhf_fast(c);
            hsp[(size_t)t * 256] = __float2bfloat16(h);
            float hp = __shfl_xor(h, 1);
            if (!(tid & 1)) {
                hf2 p; p.x = (_Float16)h; p.y = (_Float16)hp;
                hpair[tid >> 1] = __builtin_bit_cast(u32, p);
            }
        }
        __syncthreads();
    }
    if (tid < 256) {
        hf2 p = __builtin_bit_cast(hf2, hpair[tid >> 1]);
        hstate[b * 256 + tid] = (float)((tid & 1) ? p.y : p.x);
        cstate[b * 256 + tid] = c;
    }
}

// ---------- launch ----------
extern "C" void kernel_launch(void* const* d_in, const int* in_sizes, int n_in,
                              void* d_out, int out_size, void* d_ws, size_t ws_size,
                              hipStream_t stream) {
    const void* X    = d_in[0];  // [64,2048,128] fp32 (sniffed)
    const void* Wx   = d_in[1];  // [128,1024]
    const void* Wh   = d_in[2];  // [256,1024]
    const void* bg   = d_in[3];  // [1024]
    const void* Wout = d_in[4];  // [256,128]
    const void* bout = d_in[5];  // [128]
    float* out = (float*)d_out;  // [64,2048,128] fp32 (reference output dtype)

    // workspace layout (~47.2 MB)
    char* ws = (char*)d_ws;
    _Float16* xg_c        = (_Float16*)(ws + 0);                 // 33554432
    __hip_bfloat16* Xc_b  = (__hip_bfloat16*)(ws + 33554432);    //  4194304
    __hip_bfloat16* hs_c  = (__hip_bfloat16*)(ws + 37748736);    //  8388608
    uint4* Whq            = (uint4*)(ws + 46137344);             //   524288
    __hip_bfloat16* Wxb   = (__hip_bfloat16*)(ws + 46661632);    //   262144
    __hip_bfloat16* Woutb = (__hip_bfloat16*)(ws + 46923776);    //    65536
    __hip_bfloat16* bgb   = (__hip_bfloat16*)(ws + 46989312);    //     2048
    __hip_bfloat16* boutb = (__hip_bfloat16*)(ws + 46991360);    //      512
    float* hstate         = (float*)(ws + 46991872);             //    65536
    float* cstate         = (float*)(ws + 47057408);             //    65536
    int* flags            = (int*)(ws + 47122944);               //       64

    // 1) per-tensor dtype sniff
    for (int i = 0; i < 6; ++i)
        sniff<<<dim3(1), dim3(256), 0, stream>>>((const u32*)d_in[i],
                                                 in_sizes[i] / 2, flags + i);
    // 2) canonicalize weights/biases to bf16 (and Wh to quad-major fp16 pairs)
    conv_any<<<dim3(512), dim3(256), 0, stream>>>(Wx, Wxb, 131072, flags + 1);
    conv_any<<<dim3(128), dim3(256), 0, stream>>>(Wout, Woutb, 32768, flags + 4);
    conv_any<<<dim3(4),   dim3(256), 0, stream>>>(bg, bgb, 1024, flags + 3);
    conv_any<<<dim3(1),   dim3(256), 0, stream>>>(bout, boutb, 128, flags + 5);
    pack_whq<<<dim3(128), dim3(256), 0, stream>>>(Wh, Whq, flags + 2);

    for (int tc = 0; tc < NCHUNK; ++tc) {
        // 3) X chunk -> bf16 [64][256][128]
        conv_x<<<dim3(8192), dim3(256), 0, stream>>>(X, Xc_b, tc, flags + 0);
        // 4) xg_c = Xc_b @ Wxb + bgb : M=16384, N=1024, K=128
        gemm_bias<_Float16><<<dim3(16, 256), dim3(256), 0, stream>>>(
            Xc_b, Wxb, bgb, xg_c, 1024, 128, 256L, 256L);
        // 5) recurrence over TC steps
        lstm_rec_chunk<<<dim3(64), dim3(1024), 0, stream>>>(
            xg_c, Whq, hs_c, hstate, cstate, tc == 0 ? 1 : 0);
        // 6) outc = hs_c @ Woutb + boutb : M=16384, N=128, K=256  (fp32 out)
        float* outc = out + (size_t)tc * TC * 128;
        gemm_bias<float><<<dim3(2, 256), dim3(256), 0, stream>>>(
            hs_c, Woutb, boutb, outc, 128, 256, 256L, 2048L);
    }
}